// Round 2
// baseline (292.127 us; speedup 1.0000x reference)
//
#include <hip/hip_runtime.h>
#include <hip/hip_bf16.h>

// ---------------------------------------------------------------------------
// DenseCorr2d_full — FUSED corr+merge on MFMA bf16 (round 6).
//
// vs round 5: corr tm halo stored as 4 shift-copies so each MFMA B-frag is a
// single 16B ds_read2_b64 (was 4x ds_read_b32) with ~2-way banks (was ~4-way,
// 7.25M conflict cycles). Slab = 2 cm (8 slabs): smT 20.8KB + smC 27.2KB =
// 48KB LDS. bq reloaded per slab (asm-opaqued vs LICM) to shrink live regs.
// ws layout: Wb bf16 [9][64][256] only.
// ---------------------------------------------------------------------------

typedef __attribute__((ext_vector_type(4))) float  f32x4;
typedef __attribute__((ext_vector_type(8))) short  bf16x8;

__device__ inline unsigned int pack_bf16x2(float a, float b) {
    unsigned int ua = __builtin_bit_cast(unsigned int, a);
    unsigned int ub = __builtin_bit_cast(unsigned int, b);
    ua = (ua + 0x7fffu + ((ua >> 16) & 1u)) >> 16;   // RNE
    ub = (ub + 0x7fffu + ((ub >> 16) & 1u)) >> 16;
    return ua | (ub << 16);
}
__device__ inline unsigned short cvt1(float f) {
    unsigned int u = __builtin_bit_cast(unsigned int, f);
    return (unsigned short)((u + 0x7fffu + ((u >> 16) & 1u)) >> 16);
}

// ---------------- W transform: [co][cin][3][3] fp32 -> Wb[kk][co][256] bf16 -
__global__ __launch_bounds__(256) void wt_kernel(
    const float* __restrict__ W, unsigned short* __restrict__ Wb)
{
    int idx = (int)blockIdx.x * 256 + (int)threadIdx.x;   // < 9*64*256
    int c  = idx & 255;
    int rem = idx >> 8;
    int co = rem % 64;
    int kk = rem / 64;
    Wb[idx] = cvt1(W[(size_t)co * 2304 + (size_t)c * 9 + kk]);
}

// ---------------- Fused corr + 3x3 SAME merge conv --------------------------
__global__ __launch_bounds__(512, 4) void fused_mfma(
    const float* __restrict__ tp, const float* __restrict__ tm,
    const unsigned short* __restrict__ Wb, const float* __restrict__ bias,
    float* __restrict__ out)
{
    // tm halo, 4 shift-copies: [cm 2][copy 4][row 25][pitch 52] = 20800 B
    __shared__ __align__(16) unsigned short smT[2 * 4 * 25 * 52];
    // corr slab for merge: [10 rows][34 cols][40 ch-pitch] = 27200 B
    __shared__ __align__(16) unsigned short smC[10 * 34 * 40];

    const int t    = threadIdx.x;
    const int wave = t >> 6, lane = t & 63;
    const int n    = lane & 15, quad = lane >> 4;
    const int qh   = quad >> 1, jq = quad & 1;

    const int x0 = (int)blockIdx.x << 5;   // 0..96
    const int y0 = (int)blockIdx.y << 3;   // 0..120
    const int b  = (int)blockIdx.z;

    f32x4 acc[4][2];                       // merge accumulators [ct][x-half]
#pragma unroll
    for (int a = 0; a < 4; ++a)
#pragma unroll
        for (int q = 0; q < 2; ++q) acc[a][q] = (f32x4){0.f, 0.f, 0.f, 0.f};

#pragma unroll 1
    for (int s = 0; s < 8; ++s) {
        // ---- 1. stage tm halo for cm = 2s, 2s+1 into 4 shift-copies ----
        {
            const float* tmb = tm + ((size_t)(b * 16 + (s << 1)) << 14);
#pragma unroll 1
            for (int e = t; e < 2450; e += 512) {     // 2 cm * 25 r * 49 c
                int cm  = e >= 1225 ? 1 : 0;
                int rem = e - (cm ? 1225 : 0);
                int r   = rem / 49;
                int c   = rem - 49 * r;
                int gy = y0 - 1 + r; gy = gy < 0 ? 0 : (gy > 127 ? 127 : gy);
                int gx = x0 - 1 + c; gx = gx < 0 ? 0 : (gx > 127 ? 127 : gx);
                unsigned short h = cvt1(tmb[((size_t)cm << 14) + (gy << 7) + gx]);
                int a0 = (cm * 100 + r) * 52 + c;     // copy 0 (cm*4*25 rows)
                smT[a0] = h;                          // copy c' at +c'*1300-c'
                if (c >= 1) smT[a0 + 1299] = h;
                if (c >= 2) smT[a0 + 2598] = h;
                if (c >= 3) smT[a0 + 3897] = h;
            }
        }

        // ---- corr A-frags (reloaded per slab; asm keeps it out of LICM so
        //      the 32 regs don't stay live across the merge phase) ----
        bf16x8 bq[8];
        {
            const float* tpb = tp + (((size_t)(b * 16 + n)) << 8);
            asm volatile("" : "+v"(tpb));             // defeat hoisting
#pragma unroll
            for (int kc = 0; kc < 8; ++kc) {
                const float4* q = (const float4*)(tpb + (((2 * kc + qh) << 4) + (jq << 3)));
                float4 a = q[0], c4 = q[1];
                union { uint4 u; bf16x8 h; } cv;
                cv.u.x = pack_bf16x2(a.x, a.y);
                cv.u.y = pack_bf16x2(a.z, a.w);
                cv.u.z = pack_bf16x2(c4.x, c4.y);
                cv.u.w = pack_bf16x2(c4.z, c4.w);
                bq[kc] = cv.h;
            }
        }
        __syncthreads();   // smT ready; all waves past merge(s-1) -> smC free

        // ---- 2. corr: 44 groups = 2 cm x 22 pixel-tiles over 8 waves ----
#pragma unroll 1
        for (int i = 0; i < 6; ++i) {
            const int g = i * 8 + wave;
            if (g < 44) {
                const int j  = g & 1;             // cm_local 0/1
                const int tl = g >> 1;            // pixel tile 0..21
                const int p  = (tl << 4) + n;     // flat halo pixel 0..351
                const int pc = p < 340 ? p : 339; // clamp tail lanes (no store)
                const int py = pc / 34;
                const int px = pc - 34 * py;
                const int cs = px & 3;            // shift-copy select
                // 8B-aligned window start (px&~3)+jq*8 in copy cs
                const int base = ((j * 4 + cs) * 25 + py + qh) * 52
                               + (px & ~3) + (jq << 3);
                const uint2* qp = (const uint2*)&smT[base];
                f32x4 a4a = (f32x4){0.f, 0.f, 0.f, 0.f};
                f32x4 a4b = (f32x4){0.f, 0.f, 0.f, 0.f};
#pragma unroll
                for (int kc = 0; kc < 8; ++kc) {
                    uint2 lo = qp[kc * 26];       // ds_read2_b64 pair
                    uint2 hi = qp[kc * 26 + 1];
                    union { uint4 u; bf16x8 h; } fr;
                    fr.u.x = lo.x; fr.u.y = lo.y; fr.u.z = hi.x; fr.u.w = hi.y;
                    if (kc & 1)
                        a4b = __builtin_amdgcn_mfma_f32_16x16x32_bf16(
                            bq[kc], fr.h, a4b, 0, 0, 0);
                    else
                        a4a = __builtin_amdgcn_mfma_f32_16x16x32_bf16(
                            bq[kc], fr.h, a4a, 0, 0, 0);
                }
                f32x4 a4 = a4a + a4b;
                // D[row=quad*4+r = ct][col=n = pixel]; ch = j*16+quad*4+r
                const int gy = y0 - 1 + py, gx = x0 - 1 + px;
                const bool valid = ((unsigned)gy < 128u) && ((unsigned)gx < 128u);
                uint2 v;
                v.x = valid ? pack_bf16x2(a4[0], a4[1]) : 0u;  // SAME-pad zero
                v.y = valid ? pack_bf16x2(a4[2], a4[3]) : 0u;
                if (p < 340)
                    *(uint2*)&smC[p * 40 + (j << 4) + (quad << 2)] = v;
            }
        }
        __syncthreads();   // smC ready; smT free for next slab

        // ---- 3. merge on slab channels c0 = 32s (1 k-chunk per kk) ----
        {
            const unsigned short* wpb = Wb + (size_t)n * 256 + (s << 5) + (quad << 3);
            bf16x8 afc[4];
#pragma unroll
            for (int ct = 0; ct < 4; ++ct)
                afc[ct] = *(const bf16x8*)(wpb + (size_t)ct * 4096);
#pragma unroll 1
            for (int kk = 0; kk < 9; ++kk) {
                const int nkk = kk < 8 ? kk + 1 : 8;
                bf16x8 afn[4];
#pragma unroll
                for (int ct = 0; ct < 4; ++ct)
                    afn[ct] = *(const bf16x8*)(wpb + (size_t)nkk * 16384
                                                   + (size_t)ct * 4096);
                const int dy = (kk * 11) >> 5;          // kk/3 for kk<9
                const int dx = kk - 3 * dy;
#pragma unroll
                for (int nt = 0; nt < 2; ++nt) {
                    const int prow = wave + dy;          // wave = out row
                    const int pcol = (nt << 4) + n + dx;
                    bf16x8 bf = *(const bf16x8*)&smC[prow * 1360 + pcol * 40
                                                     + (quad << 3)];
#pragma unroll
                    for (int ct = 0; ct < 4; ++ct)
                        acc[ct][nt] = __builtin_amdgcn_mfma_f32_16x16x32_bf16(
                            afc[ct], bf, acc[ct][nt], 0, 0, 0);
                }
#pragma unroll
                for (int ct = 0; ct < 4; ++ct) afc[ct] = afn[ct];
            }
        }
        // next slab: stage writes smT (disjoint from smC) then barriers
        // before corr touches smC -> 2 barriers per slab suffice
    }

    // ---- epilogue: D[row=quad*4+r = co][col=n], + bias, fp32 out ----
#pragma unroll
    for (int ct = 0; ct < 4; ++ct) {
#pragma unroll
        for (int nt = 0; nt < 2; ++nt) {
            const int y   = y0 + wave;
            const int x   = x0 + (nt << 4) + n;
            const int co0 = (ct << 4) + (quad << 2);
            float* op = out + (((size_t)((b << 6) + co0) << 7) + y) * 128 + x;
#pragma unroll
            for (int r = 0; r < 4; ++r)
                op[(size_t)r << 14] = acc[ct][nt][r] + bias[co0 + r];
        }
    }
}

extern "C" void kernel_launch(void* const* d_in, const int* in_sizes, int n_in,
                              void* d_out, int out_size, void* d_ws, size_t ws_size,
                              hipStream_t stream)
{
    const float* tp   = (const float*)d_in[0];   // template [8,16,16,16]
    const float* tm   = (const float*)d_in[1];   // tomatch  [8,16,128,128]
    const float* Wt   = (const float*)d_in[2];   // W        [64,256,3,3]
    const float* bias = (const float*)d_in[3];   // b        [64]
    float* out = (float*)d_out;                  // [8,64,128,128] fp32

    unsigned short* Wb = (unsigned short*)d_ws;  // 294 KB

    wt_kernel<<<dim3(576), dim3(256), 0, stream>>>(Wt, Wb);
    fused_mfma<<<dim3(4, 16, 8), dim3(512), 0, stream>>>(tp, tm, Wb, bias, out);
}